// Round 7
// baseline (180.091 us; speedup 1.0000x reference)
//
#include <hip/hip_runtime.h>

#define NCB 32
#define KK 16
#define DD 128
#define IN_F 4096
#define OUT_F 2048
#define NTOK 2048

#define LUT_BLOCKS 128                      // 32 c x 4 o-tiles of 512
#define IDX_TILE 16                         // tokens per wave
#define IDX_WAVES (NCB * (NTOK / IDX_TILE)) // 4096 waves
#define IDX_BLOCKS (IDX_WAVES / 4)          // 1024 blocks

// ---- Launch A: grid-partitioned fusion of lut-build and idx-argmin ----
__global__ __launch_bounds__(256) void fused_lut_idx(
    const float* __restrict__ centroids, const float* __restrict__ weight,
    const float* __restrict__ x, float* __restrict__ lut,
    unsigned char* __restrict__ idxb) {
    __shared__ float cent[KK * DD];  // 8 KB (lut branch only)
    const int tid = threadIdx.x;

    if (blockIdx.x < LUT_BLOCKS) {
        // lut[c][k][o] = sum_d cent[c][k][d] * W[c][d][o]
        // cent in LDS (ds_read CANNOT be scalarized -> no SMEM serialization).
        // thread = 2 consecutive o's; weight read once, coalesced.
        const int c = blockIdx.x >> 2;
        const int o = ((blockIdx.x & 3) << 9) | (tid << 1);
        {
            const float4* cb = (const float4*)(centroids + (size_t)c * KK * DD);
            for (int i = tid; i < KK * DD / 4; i += 256) ((float4*)cent)[i] = cb[i];
        }
        __syncthreads();

        float2 acc[KK];
#pragma unroll
        for (int k = 0; k < KK; ++k) acc[k] = make_float2(0.f, 0.f);
        const float* wb = weight + (size_t)c * DD * OUT_F + o;
#pragma unroll 2
        for (int d4 = 0; d4 < DD / 4; ++d4) {
            float2 w0 = *(const float2*)(wb + (size_t)(d4 * 4 + 0) * OUT_F);
            float2 w1 = *(const float2*)(wb + (size_t)(d4 * 4 + 1) * OUT_F);
            float2 w2 = *(const float2*)(wb + (size_t)(d4 * 4 + 2) * OUT_F);
            float2 w3 = *(const float2*)(wb + (size_t)(d4 * 4 + 3) * OUT_F);
#pragma unroll
            for (int k = 0; k < KK; ++k) {
                float4 cv = *(const float4*)(cent + k * DD + d4 * 4);  // LDS broadcast
                acc[k].x += cv.x * w0.x + cv.y * w1.x + cv.z * w2.x + cv.w * w3.x;
                acc[k].y += cv.x * w0.y + cv.y * w1.y + cv.z * w2.y + cv.w * w3.y;
            }
        }
#pragma unroll
        for (int k = 0; k < KK; ++k)
            *(float2*)(lut + ((size_t)c * KK + k) * OUT_F + o) = acc[k];
    } else {
        // idx[t][c] = argmin_k (|cent[c][k]|^2 - 2 x[t].cent[c][k])
        // Pure register/shuffle: wave = 16 k x 4 d-quarters; NO LDS, no barriers.
        const int g = (blockIdx.x - LUT_BLOCKS) * 4 + (tid >> 6);
        const int c = g & (NCB - 1);
        const int t0 = (g >> 5) * IDX_TILE;
        const int lane = tid & 63;
        const int k = lane >> 2;
        const int dq = lane & 3;

        // centroid fragment: 32 floats per lane, resident for the whole wave
        const float4* cp = (const float4*)(centroids + ((size_t)c * KK + k) * DD + dq * 32);
        float4 cr[8];
#pragma unroll
        for (int j = 0; j < 8; ++j) cr[j] = cp[j];

        float sq = 0.f;
#pragma unroll
        for (int j = 0; j < 8; ++j)
            sq += cr[j].x * cr[j].x + cr[j].y * cr[j].y
                + cr[j].z * cr[j].z + cr[j].w * cr[j].w;
        sq += __shfl_xor(sq, 1);
        sq += __shfl_xor(sq, 2);  // all 4 dq-lanes now hold |cent[c][k]|^2

        const float* xp = x + (size_t)t0 * IN_F + c * DD + dq * 32;
        for (int tt = 0; tt < IDX_TILE; ++tt) {
            const float4* xv = (const float4*)(xp + (size_t)tt * IN_F);
            float dot = 0.f;
#pragma unroll
            for (int j = 0; j < 8; ++j) {
                float4 xr = xv[j];
                dot += cr[j].x * xr.x + cr[j].y * xr.y
                     + cr[j].z * xr.z + cr[j].w * xr.w;
            }
            dot += __shfl_xor(dot, 1);
            dot += __shfl_xor(dot, 2);  // full dot in all dq-lanes
            float best = sq - 2.f * dot;
            int bi = k;
#pragma unroll
            for (int s = 4; s <= 32; s <<= 1) {  // argmin over 16 k-groups
                float ov = __shfl_xor(best, s);
                int oi = __shfl_xor(bi, s);
                if (ov < best || (ov == best && oi < bi)) { best = ov; bi = oi; }
            }
            if (lane == 0)
                idxb[(size_t)(t0 + tt) * NCB + c] = (unsigned char)bi;
        }
    }
}

// ---- Launch B: out[t][o] = bias[o] + sum_c lut[c][idx[t][c]][o] ----
// L2-direct gather: block = 1 token, wave = o-quarter; every lut-row read is a
// fully-coalesced 1KB transaction; lut (4MB) lives in each XCD's L2.
__global__ __launch_bounds__(256) void gather_kernel(const float* __restrict__ lut,
                                                     const unsigned char* __restrict__ idxb,
                                                     const float* __restrict__ bias,
                                                     float* __restrict__ out) {
    const int t = blockIdx.x;
    const int f = ((threadIdx.x >> 6) << 7) | (threadIdx.x & 63);  // float4 index

    const unsigned int* ip = (const unsigned int*)(idxb + (size_t)t * NCB);  // uniform
    float4 a0 = ((const float4*)bias)[f];
    float4 a1 = ((const float4*)bias)[f + 64];

#pragma unroll
    for (int ci = 0; ci < NCB / 4; ++ci) {
        unsigned int iv4 = ip[ci];
#pragma unroll
        for (int b = 0; b < 4; ++b) {
            int c = ci * 4 + b;
            int iv = (iv4 >> (8 * b)) & 0xff;
            const float4* rp = (const float4*)(lut + ((size_t)c * KK + iv) * OUT_F);
            float4 v0 = rp[f];
            float4 v1 = rp[f + 64];
            a0.x += v0.x; a0.y += v0.y; a0.z += v0.z; a0.w += v0.w;
            a1.x += v1.x; a1.y += v1.y; a1.z += v1.z; a1.w += v1.w;
        }
    }
    float4* op = (float4*)(out + (size_t)t * OUT_F);
    op[f] = a0;
    op[f + 64] = a1;
}

extern "C" void kernel_launch(void* const* d_in, const int* in_sizes, int n_in,
                              void* d_out, int out_size, void* d_ws, size_t ws_size,
                              hipStream_t stream) {
    const float* x         = (const float*)d_in[0];  // [2,1024,4096]
    const float* centroids = (const float*)d_in[1];  // [32,16,128]
    const float* weight    = (const float*)d_in[2];  // [32,128,2048]
    const float* bias      = (const float*)d_in[4];  // [2048]
    float* out = (float*)d_out;                      // [2048,2048] fp32

    float* lut = (float*)d_ws;                                // 4 MB
    unsigned char* idxb = (unsigned char*)d_ws + (4u << 20);  // 64 KB

    fused_lut_idx<<<LUT_BLOCKS + IDX_BLOCKS, 256, 0, stream>>>(
        centroids, weight, x, lut, idxb);
    gather_kernel<<<NTOK, 256, 0, stream>>>(lut, idxb, bias, out);
}

// Round 8
// 176.688 us; speedup vs baseline: 1.0193x; 1.0193x over previous
//
#include <hip/hip_runtime.h>

#define NCB 32
#define KK 16
#define DD 128
#define IN_F 4096
#define OUT_F 2048
#define NTOK 2048

#define LUT_BLOCKS 128   // 32 c x 4 o-tiles of 512
#define IDX_TILE 16      // tokens per wave
#define IDX_BLOCKS (NCB * (NTOK / IDX_TILE) / 4)  // 1024 (4 waves/block)

// ---- K1: lut[c][k][o] = sum_d cent[c][k][d] * W[c][d][o] ----
// cent in LDS (ds_read cannot scalarize -> no SMEM serialization); weight read
// once, coalesced, 32 independent loads in flight per thread.
__global__ __launch_bounds__(256) void lut_kernel(
    const float* __restrict__ centroids, const float* __restrict__ weight,
    float* __restrict__ lut) {
    __shared__ float cent[KK * DD];  // 8 KB
    const int tid = threadIdx.x;
    const int c = blockIdx.x >> 2;
    const int o = ((blockIdx.x & 3) << 9) | (tid << 1);
    {
        const float4* cb = (const float4*)(centroids + (size_t)c * KK * DD);
        for (int i = tid; i < KK * DD / 4; i += 256) ((float4*)cent)[i] = cb[i];
    }
    __syncthreads();

    float2 acc[KK];
#pragma unroll
    for (int k = 0; k < KK; ++k) acc[k] = make_float2(0.f, 0.f);
    const float* wb = weight + (size_t)c * DD * OUT_F + o;
#pragma unroll 2
    for (int d4 = 0; d4 < DD / 4; ++d4) {
        float2 w0 = *(const float2*)(wb + (size_t)(d4 * 4 + 0) * OUT_F);
        float2 w1 = *(const float2*)(wb + (size_t)(d4 * 4 + 1) * OUT_F);
        float2 w2 = *(const float2*)(wb + (size_t)(d4 * 4 + 2) * OUT_F);
        float2 w3 = *(const float2*)(wb + (size_t)(d4 * 4 + 3) * OUT_F);
#pragma unroll
        for (int k = 0; k < KK; ++k) {
            float4 cv = *(const float4*)(cent + k * DD + d4 * 4);  // LDS broadcast
            acc[k].x += cv.x * w0.x + cv.y * w1.x + cv.z * w2.x + cv.w * w3.x;
            acc[k].y += cv.x * w0.y + cv.y * w1.y + cv.z * w2.y + cv.w * w3.y;
        }
    }
#pragma unroll
    for (int k = 0; k < KK; ++k)
        *(float2*)(lut + ((size_t)c * KK + k) * OUT_F + o) = acc[k];
}

// ---- K2: idx[t][c] = argmin_k (|cent[c][k]|^2 - 2 x[t].cent[c][k]) ----
// Wave = 16 k x 4 d-quarters. Wave-local LDS staging of the 16-token x slice:
// 8 coalesced global loads in flight at once (one latency exposure per wave),
// then the token loop runs from LDS. dq-stride 36 floats -> disjoint bank
// quads {0-3,4-7,8-11,12-15}: conflict-free 16-lane-broadcast ds_read_b128.
__global__ __launch_bounds__(256) void idx_kernel(
    const float* __restrict__ centroids, const float* __restrict__ x,
    unsigned char* __restrict__ idxb) {
    __shared__ float xls[4 * IDX_TILE * 144];  // 36 KB, per-wave 9 KB regions
    const int tid = threadIdx.x;
    const int warp = tid >> 6;
    const int lane = tid & 63;
    const int g = blockIdx.x * 4 + warp;
    const int c = g & (NCB - 1);
    const int t0 = (g >> 5) * IDX_TILE;
    const int k = lane >> 2;
    const int dq = lane & 3;
    float* xw = xls + warp * (IDX_TILE * 144);

    // centroid fragment: 32 floats/lane, resident all wave
    const float4* cp = (const float4*)(centroids + ((size_t)c * KK + k) * DD + dq * 32);
    float4 cr[8];
#pragma unroll
    for (int j = 0; j < 8; ++j) cr[j] = cp[j];

    // stage 16 tokens x 128 floats: instr i covers 2 token rows x 512 B contig
    {
        const float* xg = x + (size_t)t0 * IN_F + c * DD;
#pragma unroll
        for (int i = 0; i < 8; ++i) {
            int p = i * 64 + lane;
            int tok = p >> 5, f4 = p & 31;
            float4 v = *(const float4*)(xg + (size_t)tok * IN_F + f4 * 4);
            *(float4*)(xw + tok * 144 + (f4 >> 3) * 36 + (f4 & 7) * 4) = v;
        }
    }

    float sq = 0.f;
#pragma unroll
    for (int j = 0; j < 8; ++j)
        sq += cr[j].x * cr[j].x + cr[j].y * cr[j].y
            + cr[j].z * cr[j].z + cr[j].w * cr[j].w;
    sq += __shfl_xor(sq, 1);
    sq += __shfl_xor(sq, 2);  // all 4 dq-lanes hold |cent[c][k]|^2

    for (int tt = 0; tt < IDX_TILE; ++tt) {
        const float* xr = xw + tt * 144 + dq * 36;
        float dot = 0.f;
#pragma unroll
        for (int j = 0; j < 8; ++j) {
            float4 xv = *(const float4*)(xr + j * 4);
            dot += cr[j].x * xv.x + cr[j].y * xv.y
                 + cr[j].z * xv.z + cr[j].w * xv.w;
        }
        dot += __shfl_xor(dot, 1);
        dot += __shfl_xor(dot, 2);
        float best = sq - 2.f * dot;
        int bi = k;
#pragma unroll
        for (int s = 4; s <= 32; s <<= 1) {  // argmin over 16 k-groups, first-idx tie-break
            float ov = __shfl_xor(best, s);
            int oi = __shfl_xor(bi, s);
            if (ov < best || (ov == best && oi < bi)) { best = ov; bi = oi; }
        }
        if (lane == 0)
            idxb[(size_t)(t0 + tt) * NCB + c] = (unsigned char)bi;
    }
}

// ---- K3: out[t][o] = bias[o] + sum_c lut[c][idx[t][c]][o] ----
// L2-direct gather: block = 1 token; every lut-row read is a coalesced 1 KB
// transaction; lut (4 MB) is L2-resident. idx row is uniform -> scalar loads.
__global__ __launch_bounds__(256) void gather_kernel(const float* __restrict__ lut,
                                                     const unsigned char* __restrict__ idxb,
                                                     const float* __restrict__ bias,
                                                     float* __restrict__ out) {
    const int t = blockIdx.x;
    const int f = ((threadIdx.x >> 6) << 7) | (threadIdx.x & 63);  // float4 index

    const unsigned int* ip = (const unsigned int*)(idxb + (size_t)t * NCB);  // uniform
    float4 a0 = ((const float4*)bias)[f];
    float4 a1 = ((const float4*)bias)[f + 64];

#pragma unroll
    for (int ci = 0; ci < NCB / 4; ++ci) {
        unsigned int iv4 = ip[ci];
#pragma unroll
        for (int b = 0; b < 4; ++b) {
            int c = ci * 4 + b;
            int iv = (iv4 >> (8 * b)) & 0xff;
            const float4* rp = (const float4*)(lut + ((size_t)c * KK + iv) * OUT_F);
            float4 v0 = rp[f];
            float4 v1 = rp[f + 64];
            a0.x += v0.x; a0.y += v0.y; a0.z += v0.z; a0.w += v0.w;
            a1.x += v1.x; a1.y += v1.y; a1.z += v1.z; a1.w += v1.w;
        }
    }
    float4* op = (float4*)(out + (size_t)t * OUT_F);
    op[f] = a0;
    op[f + 64] = a1;
}

extern "C" void kernel_launch(void* const* d_in, const int* in_sizes, int n_in,
                              void* d_out, int out_size, void* d_ws, size_t ws_size,
                              hipStream_t stream) {
    const float* x         = (const float*)d_in[0];  // [2,1024,4096]
    const float* centroids = (const float*)d_in[1];  // [32,16,128]
    const float* weight    = (const float*)d_in[2];  // [32,128,2048]
    const float* bias      = (const float*)d_in[4];  // [2048]
    float* out = (float*)d_out;                      // [2048,2048] fp32

    float* lut = (float*)d_ws;                                // 4 MB
    unsigned char* idxb = (unsigned char*)d_ws + (4u << 20);  // 64 KB

    lut_kernel<<<LUT_BLOCKS, 256, 0, stream>>>(centroids, weight, lut);
    idx_kernel<<<IDX_BLOCKS, 256, 0, stream>>>(centroids, x, idxb);
    gather_kernel<<<NTOK, 256, 0, stream>>>(lut, idxb, bias, out);
}